// Round 13
// baseline (31.229 us; speedup 1.0000x reference)
//
#include <hip/hip_runtime.h>
#include <cstdint>

typedef unsigned short u16;
typedef unsigned int u32;
typedef unsigned short us2 __attribute__((ext_vector_type(2)));

constexpr int BB = 16, HH = 512, WW = 512;
constexpr int NPIX = BB * HH * WW;       // 4,194,304
constexpr int XT = 16, HALO = 16;
constexpr int TR  = XT + 2 * HALO;       // 48 tile rows
constexpr int CDW = TR / 2 + 1;          // 25 dwords per padded LDS column
constexpr int NBX = HH / XT;             // 32
constexpr int NBLK = NBX * BB;           // 512 blocks

__device__ __forceinline__ us2 pmax2(us2 a, us2 b) { return __builtin_elementwise_max(a, b); }
__device__ __forceinline__ us2 pmin2(us2 a, us2 b) { return __builtin_elementwise_min(a, b); }
__device__ __forceinline__ us2 U2(u32 x) { return __builtin_bit_cast(us2, x); }
__device__ __forceinline__ u32 B2(us2 x) { return __builtin_bit_cast(u32, x); }

// ---- envelope body for one pixel, parity P (verified exact in R8) -----------
// Tile dword = rowEven u16 | rowOdd<<16, u16 = pos8 | neg8<<8 (one byte is 0;
// sentinel 0x7f7f on OOB rows). Window of 8 dwords covers dy<=7 both sides;
// rare wave-uniform deep fallback extends exactly to dy<=HALO.
template <int P>
__device__ __forceinline__ void body(const u32* __restrict__ colp, int e,
                                     const float* __restrict__ ip,
                                     float& aP, float& aTP, float& aS,
                                     u32& aM, int& aC) {
  constexpr u32 K[2][8] = {
    {64|(49u<<16),36|(25u<<16),16|(9u<<16),4|(1u<<16),0|(1u<<16),4|(9u<<16),16|(25u<<16),36|(49u<<16)},
    {49|(36u<<16),25|(16u<<16),9|(4u<<16),1|(0u<<16),1|(4u<<16),9|(16u<<16),25|(36u<<16),49|(64u<<16)}};
  const int s = e + P - 4;
  u32 w[8];
  #pragma unroll
  for (int i = 0; i < 8; ++i) w[i] = colp[s + i];
  const u32 own = w[4 - P];
  const u32 o = (P == 0) ? (own & 0xffffu) : (own >> 16);
  const bool fg = (o & 0xffu) != 0;
  const int uo = (int)((o | (o >> 8)) & 0xffu);
  const us2 shv = U2(fg ? 0u : 0x00080008u);
  us2 best = U2(0xffffffffu);
  #pragma unroll
  for (int i = 0; i < 8; ++i) {
    us2 mm = U2(B2((us2)(U2(w[i]) >> shv)) & 0x00ff00ffu);
    best = pmin2(best, (us2)(mm * mm + U2(K[P][i])));
  }
  u32 bst = min((u32)best[0], (u32)best[1]);
  if (__any(uo > 8)) {                       // rare exact fallback, dy 8..HALO
    const int rl = 2 * e + P;
    const int sh8 = fg ? 0 : 8;
    #pragma unroll 1
    for (int dy = 8; dy <= HALO; ++dy) {
      int r1 = rl + dy, r2 = rl - dy;
      u32 d1w = colp[r1 >> 1], d2w = colp[r2 >> 1];
      int u1 = (int)((d1w >> (((r1 & 1) * 16) + sh8)) & 0xffu);
      int u2 = (int)((d2w >> (((r2 & 1) * 16) + sh8)) & 0xffu);
      int q = dy * dy;
      bst = min(bst, (u32)(u1 * u1 + q));
      bst = min(bst, (u32)(u2 * u2 + q));
    }
  }
  float D = sqrtf((float)bst);               // = posdis + negdis at this pixel
  float v = *ip;
  float p = 1.0f / (1.0f + __expf(-v));
  aP += p;
  if (fg) { aTP += p; aC += 1; aS -= p * D; } else { aS += p * D; }
  aM = max(aM, bst);
}

// ---- fused kernel: in-block packed scans -> LDS -> envelope -> plain stores -
__global__ void __launch_bounds__(256)
k_fused(const float* __restrict__ inp, const int* __restrict__ tg,
        float* __restrict__ partS, u32* __restrict__ partM,
        float* __restrict__ partP, float* __restrict__ partTP,
        int* __restrict__ partT) {
  __shared__ u32 tile[512 * CDW];            // column-major, 2 rows per dword
  const int tid = threadIdx.x, wv = tid >> 6, lane = tid & 63, c0 = lane * 8;
  const int xt = blockIdx.x, b = blockIdx.y, x0 = xt * XT;
  const int* tgb = tg + (size_t)b * HH * WW;

  // ---- phase 1: packed dual-row boundary scans, rows [x0-HALO, x0+XT+HALO) --
  #pragma unroll 1
  for (int q = 0; q < 6; ++q) {
    const int rl = wv * 12 + 2 * q;          // local tile row (even of pair)
    const int gA = x0 - HALO + rl;
    const bool okA = (unsigned)gA < (unsigned)HH;
    const bool okB = (unsigned)(gA + 1) < (unsigned)HH;
    const int ga = okA ? gA : 0, gb = okB ? gA + 1 : 0;
    const int* rpA = tgb + (size_t)ga * WW + c0;
    const int* rpB = tgb + (size_t)gb * WW + c0;
    int4 a0 = *(const int4*)rpA, a1 = *(const int4*)(rpA + 4);
    int4 b0 = *(const int4*)rpB, b1 = *(const int4*)(rpB + 4);
    int tA[8] = {a0.x, a0.y, a0.z, a0.w, a1.x, a1.y, a1.z, a1.w};
    int tB[8] = {b0.x, b0.y, b0.z, b0.w, b1.x, b1.y, b1.z, b1.w};
    u32 tp[8];
    #pragma unroll
    for (int k = 0; k < 8; ++k) tp[k] = (u32)tA[k] | ((u32)tB[k] << 16);
    u32 tprev = __shfl_up(tp[7], 1);  if (lane == 0)  tprev = tp[0];
    u32 tnext = __shfl_down(tp[0], 1); if (lane == 63) tnext = tp[7];

    // fwd: prefix max of (boundary-at-i ? i+2048 : 0), both rows packed u16
    u32 lm[8]; us2 m = U2(0);
    #pragma unroll
    for (int k = 0; k < 8; ++k) {
      u32 prev = k ? tp[k - 1] : tprev;
      us2 diff = U2(tp[k] ^ prev);           // 0/1 per half (targets are 0/1)
      us2 ib = U2((u32)(c0 + k + 2048) * 0x10001u);
      m = pmax2(m, (us2)(diff * ib));
      lm[k] = B2(m);
    }
    u32 X = B2(m);
    #pragma unroll
    for (int off = 1; off < 64; off <<= 1) {
      u32 y = __shfl_up(X, off);
      if (lane >= off) X = B2(pmax2(U2(X), U2(y)));
    }
    u32 E = __shfl_up(X, 1); if (lane == 0) E = 0;

    // bwd: suffix min of (boundary-at-i ? i+2048 : 4607)
    u32 sm[8]; us2 m2 = U2(0x11ff11ffu);
    #pragma unroll
    for (int k = 7; k >= 0; --k) {
      u32 nxt = (k < 7) ? tp[k + 1] : tnext;
      us2 diff = U2(tp[k] ^ nxt);
      us2 sb = U2((u32)(2559 - (c0 + k)) * 0x10001u);
      m2 = pmin2(m2, (us2)(U2(0x11ff11ffu) - (us2)(diff * sb)));
      sm[k] = B2(m2);
    }
    u32 X2 = B2(m2);
    #pragma unroll
    for (int off = 1; off < 64; off <<= 1) {
      u32 y = __shfl_down(X2, off);
      if (lane + off < 64) X2 = B2(pmin2(U2(X2), U2(y)));
    }
    u32 E2 = __shfl_down(X2, 1); if (lane == 63) E2 = 0x11ff11ffu;

    u32 pr[8];
    #pragma unroll
    for (int k = 0; k < 8; ++k) {
      us2 L = pmax2(U2(lm[k]), U2(E));
      us2 R = pmin2(U2(sm[k]), U2(E2));
      us2 ib = U2((u32)(c0 + k + 2048) * 0x10001u);
      us2 one = U2(0x10001u);
      us2 d1 = pmin2(pmin2((us2)(ib - L + one), (us2)(R - ib + one)), U2(0x007f007fu));
      u32 dd = B2(d1);
      u32 dA = dd & 0xffffu, dB = dd >> 16;
      u32 hA = okA ? (dA << ((tp[k] & 0xffffu) ? 0 : 8)) : 0x7f7fu;
      u32 hB = okB ? (dB << ((tp[k] >> 16) ? 0 : 8)) : 0x7f7fu;
      pr[k] = hA | (hB << 16);
    }
    const int r2 = wv * 6 + q;
    #pragma unroll
    for (int i = 0; i < 8; ++i) {            // bank-swizzled transpose writes
      int j = (i + (lane >> 2)) & 7;
      tile[(c0 + j) * CDW + r2] = pr[j];
    }
  }
  __syncthreads();

  // ---- phase 2: envelope + sigmoid + reductions (2 cols x 16 rows/thread) ---
  const u32* colp0 = tile + (size_t)tid * CDW;
  const u32* colp1 = colp0 + (size_t)256 * CDW;
  float aP = 0.f, aTP = 0.f, aS = 0.f;
  u32 aM = 0; int aC = 0;

  #pragma unroll 1
  for (int k2 = 0; k2 < 8; ++k2) {
    const int e = HALO / 2 + k2;             // own row-pair dword index
    const float* ipr = inp + ((size_t)(b * HH + x0 + 2 * k2)) * WW + tid;
    body<0>(colp0, e, ipr,            aP, aTP, aS, aM, aC);
    body<1>(colp0, e, ipr + WW,       aP, aTP, aS, aM, aC);
    body<0>(colp1, e, ipr + 256,      aP, aTP, aS, aM, aC);
    body<1>(colp1, e, ipr + WW + 256, aP, aTP, aS, aM, aC);
  }

  // wave reduce
  #pragma unroll
  for (int off = 32; off >= 1; off >>= 1) {
    aP  += __shfl_xor(aP, off);
    aTP += __shfl_xor(aTP, off);
    aS  += __shfl_xor(aS, off);
    aC  += __shfl_xor(aC, off);
    aM = max(aM, (u32)__shfl_xor((int)aM, off));
  }
  __shared__ float rP[4], rTP[4], rS[4];
  __shared__ u32 rM[4]; __shared__ int rC[4];
  if (lane == 0) { rP[wv] = aP; rTP[wv] = aTP; rS[wv] = aS; rM[wv] = aM; rC[wv] = aC; }
  __syncthreads();
  if (tid == 0) {                            // plain per-block stores, no fence
    int part = b * NBX + xt;
    partP[part]  = rP[0] + rP[1] + rP[2] + rP[3];
    partTP[part] = rTP[0] + rTP[1] + rTP[2] + rTP[3];
    partS[part]  = rS[0] + rS[1] + rS[2] + rS[3];
    partM[part]  = max(max(rM[0], rM[1]), max(rM[2], rM[3]));
    partT[part]  = rC[0] + rC[1] + rC[2] + rC[3];
  }
}

// ---------------- Kernel C: finalize scalar loss (512 slots) -----------------
__global__ void __launch_bounds__(256) k_final(const float* __restrict__ partS,
                                               const u32* __restrict__ partM,
                                               const float* __restrict__ partP,
                                               const float* __restrict__ partTP,
                                               const int* __restrict__ partT,
                                               float* __restrict__ out) {
  const int t = threadIdx.x;
  const int img = t >> 4, j = t & 15;          // 16 threads per image
  float s = 0.f, p = 0.f, tp = 0.f; int tc = 0; u32 m2 = 0;
  #pragma unroll
  for (int q = 0; q < 2; ++q) {
    int e = img * 32 + j + q * 16;
    s += partS[e]; p += partP[e]; tp += partTP[e]; tc += partT[e];
    m2 = max(m2, partM[e]);
  }
  #pragma unroll
  for (int off = 8; off >= 1; off >>= 1) {
    s  += __shfl_xor(s, off);
    p  += __shfl_xor(p, off);
    tp += __shfl_xor(tp, off);
    tc += __shfl_xor(tc, off);
    m2 = max(m2, (u32)__shfl_xor((int)m2, off));
  }
  __shared__ float shC[16], shP[16], shTP[16]; __shared__ int shT[16];
  if (j == 0) {
    float bmax = sqrtf((float)m2);
    shC[img] = (tc > 0) ? (s / (bmax + 1e-8f)) : 0.0f;   // anypos guard
    shP[img] = p; shTP[img] = tp; shT[img] = tc;
  }
  __syncthreads();
  if (t == 0) {
    float sumP = 0.f, TP = 0.f, sumT = 0.f, bl = 0.f;
    for (int i = 0; i < 16; ++i) { sumP += shP[i]; TP += shTP[i]; sumT += (float)shT[i]; bl += shC[i]; }
    float FP = sumP - TP, FN = sumT - TP;
    float tv = (TP + 1.0f) / (TP + 0.3f * FP + 0.7f * FN + 1.0f);
    float ft = powf(1.0f - tv, 1.33f);
    float dice = (2.0f * TP + 1.0f) / (sumP + sumT + 1.0f);
    float dl = 1.0f - dice;
    float blm = bl / (float)NPIX;
    if (isnan(ft)) ft = 0.0f;
    if (isnan(dl)) dl = 0.0f;
    if (isnan(blm)) blm = 0.0f;
    out[0] = 0.5f * ft + 0.3f * dl + 0.2f * blm;
  }
}

extern "C" void kernel_launch(void* const* d_in, const int* in_sizes, int n_in,
                              void* d_out, int out_size, void* d_ws, size_t ws_size,
                              hipStream_t stream) {
  const float* inp = (const float*)d_in[0];
  const int* tg = (const int*)d_in[1];
  float* out = (float*)d_out;
  char* ws = (char*)d_ws;
  float* partS  = (float*)(ws);
  u32*   partM  = (u32*)(ws + 4096);
  float* partP  = (float*)(ws + 8192);
  float* partTP = (float*)(ws + 12288);
  int*   partT  = (int*)(ws + 16384);

  hipLaunchKernelGGL(k_fused, dim3(NBX, BB), dim3(256), 0, stream,
                     inp, tg, partS, partM, partP, partTP, partT);
  hipLaunchKernelGGL(k_final, dim3(1), dim3(256), 0, stream,
                     partS, partM, partP, partTP, partT, out);
}